// Round 11
// baseline (163.385 us; speedup 1.0000x reference)
//
#include <hip/hip_runtime.h>
#include <hip/hip_bf16.h>
#include <cstdint>

typedef __bf16 bf16x8 __attribute__((ext_vector_type(8)));
typedef __bf16 bf16x2 __attribute__((ext_vector_type(2)));
typedef float f32x4 __attribute__((ext_vector_type(4)));
typedef float f32x16 __attribute__((ext_vector_type(16)));

#define E_DIM 256
#define H_DIM 512
#define TSTR 260   // padded f32 row stride

// packed f32x2 -> bf16x2 (RNE)
static __device__ __forceinline__ unsigned pkbf(float a, float b) {
    bf16x2 h;
    h[0] = (__bf16)a;
    h[1] = (__bf16)b;
    return __builtin_bit_cast(unsigned, h);
}

// ---------------- kernel 1: W1 -> bf16. mats 0/1: [mat][c][h][kk] (16x16 frag layout, for pq).
// mat 2: [kstep:16][hgrp:16][k8:2][h32:32] units of 8 bf16 (32x32x16 A-operand layout, for main).
__global__ __launch_bounds__(256)
void w1conv_kernel(const float* __restrict__ W1, __bf16* __restrict__ W1cc) {
    int blk = blockIdx.x;
    int tid = threadIdx.x;
    if (blk < 128) {
        int u = blk * 256 + tid;              // 0..32767 (mats 0,1)
        int j   = u & 3;
        int h   = (u >> 2) & 511;
        int c   = (u >> 11) & 7;
        int mat = u >> 14;                    // 0 or 1
        const float* src = W1 + (size_t)(mat * 256 + c * 32 + j * 8) * H_DIM + h;
        uint4 v;
        v.x = pkbf(src[0], src[(size_t)1 * H_DIM]);
        v.y = pkbf(src[(size_t)2 * H_DIM], src[(size_t)3 * H_DIM]);
        v.z = pkbf(src[(size_t)4 * H_DIM], src[(size_t)5 * H_DIM]);
        v.w = pkbf(src[(size_t)6 * H_DIM], src[(size_t)7 * H_DIM]);
        *(uint4*)(W1cc + ((size_t)(mat * 8 + c) * 512 + h) * 32 + j * 8) = v;
    } else {
        int v = (blk - 128) * 256 + tid;      // 0..16383 (mat 2, new layout)
        int hh    = v & 31;
        int k8    = (v >> 5) & 1;
        int hgrp  = (v >> 6) & 15;
        int kstep = v >> 10;
        int h  = hgrp * 32 + hh;
        int k0 = kstep * 16 + k8 * 8;
        const float* src = W1 + (size_t)(512 + k0) * H_DIM + h;
        uint4 o;
        o.x = pkbf(src[0], src[(size_t)1 * H_DIM]);
        o.y = pkbf(src[(size_t)2 * H_DIM], src[(size_t)3 * H_DIM]);
        o.z = pkbf(src[(size_t)4 * H_DIM], src[(size_t)5 * H_DIM]);
        o.w = pkbf(src[(size_t)6 * H_DIM], src[(size_t)7 * H_DIM]);
        *(uint4*)(W1cc + 262144 + (size_t)v * 8) = o;
    }
}

// ---------------- kernel 2: P = norm(t)@W1a + b1 ; Q = norm(d)@W1b via bf16 MFMA (16x16x32) ----
// 128 blocks x 512 thr. Block = 32 rows x 256 h. (unchanged from R10)
__global__ __launch_bounds__(512, 4)
void pq_mfma_kernel(const float* __restrict__ track, const float* __restrict__ det,
                    const __bf16* __restrict__ W1cc, const float* __restrict__ b1,
                    float* __restrict__ P, float* __restrict__ Q) {
    __shared__ __align__(16) __bf16 Ash[32 * 256];   // 16 KB
    __shared__ float sclS[32];

    int tid  = threadIdx.x;
    int lane = tid & 63;
    int wave = tid >> 6;
    int lq   = lane >> 4;
    int lc   = lane & 15;

    int blk  = blockIdx.x;
    int mat  = blk >> 6;
    int rowg = (blk >> 1) & 31;
    int half = blk & 1;
    int r0   = rowg * 32;
    int h0   = half * 256;
    const float* src = mat ? det : track;

#pragma unroll
    for (int i = 0; i < 4; ++i) {
        int row = wave * 4 + i;
        float4 x = ((const float4*)(src + (size_t)(r0 + row) * E_DIM))[lane];
        float ss = x.x*x.x + x.y*x.y + x.z*x.z + x.w*x.w;
#pragma unroll
        for (int off = 32; off > 0; off >>= 1) ss += __shfl_xor(ss, off);
        if (lane == 0) sclS[row] = 1.0f / fmaxf(sqrtf(ss), 1e-12f);
    }
    __syncthreads();

#pragma unroll
    for (int r = 0; r < 2; ++r) {
        int row = r * 16 + lc;
        float st = sclS[row];
        const float* gp = src + (size_t)(r0 + row) * E_DIM + wave * 32 + lq * 8;
        float4 t0 = *(const float4*)gp;
        float4 t1 = *(const float4*)(gp + 4);
        uint4 v;
        v.x = pkbf(t0.x * st, t0.y * st);
        v.y = pkbf(t0.z * st, t0.w * st);
        v.z = pkbf(t1.x * st, t1.y * st);
        v.w = pkbf(t1.z * st, t1.w * st);
        *(uint4*)&Ash[(size_t)(r * 512 + wave * 64 + lane) * 8] = v;
    }
    __syncthreads();

    const uint4* Wg = (const uint4*)W1cc + (mat ? 16384 : 0);
    int hb = h0 + wave * 32 + lc;
    bf16x8 bwA[2], bwB[2];
#pragma unroll
    for (int ht = 0; ht < 2; ++ht)
        bwA[ht] = __builtin_bit_cast(bf16x8, Wg[(hb + ht * 16) * 4 + lq]);

    f32x4 acc[2][2];
#pragma unroll
    for (int pt = 0; pt < 2; ++pt)
#pragma unroll
        for (int ht = 0; ht < 2; ++ht)
            acc[pt][ht] = (f32x4){0.f, 0.f, 0.f, 0.f};

#pragma unroll 2
    for (int c = 0; c < 8; ++c) {
        bf16x8* cur = (c & 1) ? bwB : bwA;
        bf16x8* nxt = (c & 1) ? bwA : bwB;
        int c1 = (c + 1) & 7;
#pragma unroll
        for (int ht = 0; ht < 2; ++ht)
            nxt[ht] = __builtin_bit_cast(bf16x8, Wg[c1 * 2048 + (hb + ht * 16) * 4 + lq]);
#pragma unroll
        for (int pt = 0; pt < 2; ++pt) {
            bf16x8 af = *(const bf16x8*)&Ash[(size_t)((pt * 8 + c) * 64 + lane) * 8];
#pragma unroll
            for (int ht = 0; ht < 2; ++ht)
                acc[pt][ht] = __builtin_amdgcn_mfma_f32_16x16x32_bf16(cur[ht], af, acc[pt][ht], 0, 0, 0);
        }
    }

    float* dst = mat ? Q : P;
#pragma unroll
    for (int ht = 0; ht < 2; ++ht) {
        int h = h0 + wave * 32 + ht * 16 + lq * 4;
        f32x4 bvv = (f32x4){0.f, 0.f, 0.f, 0.f};
        if (!mat) bvv = *(const f32x4*)&b1[h];
#pragma unroll
        for (int pt = 0; pt < 2; ++pt) {
            f32x4 o = acc[pt][ht] + bvv;
            *(f32x4*)&dst[(size_t)(r0 + pt * 16 + lc) * H_DIM + h] = o;
        }
    }
}

// ---------------- kernel 3: fused pairwise GEMM (32x32x16) + LN + SiLU + W2 dot ----------------
// grid 2048 x 512 thr (8 waves). Block: 64 pairs x 512 H; K=256 in 16 ksteps.
// D[h x pair] via mfma_32x32x16: A = W-frag (h=lane&31, k=(lane>>5)*8+reg),
// B = |t-d|-frag (pair=lane&31, same k). C/D: col=lane&31=pair, row(h)=(reg&3)+8*(reg>>2)+4*(lane>>5).
// B-regs 4-slot rotation, prefetch distance 2. t/d pre-scaled at stage. All-wave reductions.
__global__ __launch_bounds__(512, 4)
void main_kernel(const float* __restrict__ track, const float* __restrict__ det,
                 const __bf16* __restrict__ W1cc,
                 const float* __restrict__ P, const float* __restrict__ Q,
                 const float* __restrict__ gamma, const float* __restrict__ beta,
                 const float* __restrict__ W2, const float* __restrict__ b2,
                 float* __restrict__ out) {
    __shared__ __align__(16) char SMEM[49408];
    __bf16* Ash  = (__bf16*)SMEM;                     // [0,32768)  [kstep:16][pt:2][k8:2][m:32] x8bf16
    float*  tsl  = (float*)(SMEM + 32768);            // 8*TSTR f32 (pre-scaled t rows), phase 1
    float*  dsl  = (float*)(SMEM + 41088);            // phase 1
    float*  LNr1 = (float*)(SMEM + 32768);            // [64][9] phase 2 (tsl dead)
    float*  LNr2 = (float*)(SMEM + 35072);            // [64][9]
    float*  Red2 = (float*)(SMEM + 37376);            // [64][9]
    float*  MuS  = (float*)(SMEM + 39680);            // [64]
    float*  RsS  = (float*)(SMEM + 39936);            // [64]

    int tid  = threadIdx.x;
    int lane = tid & 63;
    int wave = tid >> 6;
    int l32  = lane & 31;
    int lh   = lane >> 5;     // 0/1

    int blk = blockIdx.x;
    int b   = blk >> 8;
    int n0  = ((blk >> 4) & 15) * 8;
    int m0  = (blk & 15) * 8;

    // ---- stage loads: wave w holds row w of t-slice and d-slice
    float4 tstage = ((const float4*)(track + (size_t)(b * 128 + n0 + wave) * E_DIM))[lane];
    float4 dstage = ((const float4*)(det   + (size_t)(b * 128 + m0 + wave) * E_DIM))[lane];

    // ---- B prefetch ksteps 0,1 (mat2 base = 32768 uint4)
    const uint4* Wg2 = (const uint4*)W1cc + 32768;
    bf16x8 bw[4][2];
#pragma unroll
    for (int ht = 0; ht < 2; ++ht) {
        bw[0][ht] = __builtin_bit_cast(bf16x8, Wg2[(wave * 2 + ht) * 64 + lane]);
        bw[1][ht] = __builtin_bit_cast(bf16x8, Wg2[(16 + wave * 2 + ht) * 64 + lane]);
    }

    // ---- row norms (butterfly gives all lanes the sum) + pre-scale, then LDS write
    {
        float a = tstage.x*tstage.x + tstage.y*tstage.y + tstage.z*tstage.z + tstage.w*tstage.w;
        float d = dstage.x*dstage.x + dstage.y*dstage.y + dstage.z*dstage.z + dstage.w*dstage.w;
#pragma unroll
        for (int off = 32; off > 0; off >>= 1) { a += __shfl_xor(a, off); d += __shfl_xor(d, off); }
        float st = 1.0f / fmaxf(sqrtf(a), 1e-12f);
        float sd = 1.0f / fmaxf(sqrtf(d), 1e-12f);
        tstage.x *= st; tstage.y *= st; tstage.z *= st; tstage.w *= st;
        dstage.x *= sd; dstage.y *= sd; dstage.z *= sd; dstage.w *= sd;
    }
    *(float4*)&tsl[wave * TSTR + lane * 4] = tstage;
    *(float4*)&dsl[wave * TSTR + lane * 4] = dstage;
    __syncthreads();

    // ---- A-stage: thread -> (pt=wave&1, ks0=wave>>1, k8=lh, m=l32); 4 ksteps per thread
    {
        int m   = l32;
        int pt  = wave & 1;
        int ks0 = wave >> 1;
        int p   = pt * 32 + m;
        const float* tr = tsl + (p >> 3) * TSTR;
        const float* dr = dsl + (p & 7) * TSTR;
#pragma unroll
        for (int i = 0; i < 4; ++i) {
            int kstep = i * 4 + ks0;
            int k0 = kstep * 16 + lh * 8;
            float4 t0 = *(const float4*)(tr + k0);
            float4 t1 = *(const float4*)(tr + k0 + 4);
            float4 d0 = *(const float4*)(dr + k0);
            float4 d1 = *(const float4*)(dr + k0 + 4);
            uint4 v;
            v.x = pkbf(fabsf(t0.x - d0.x), fabsf(t0.y - d0.y));
            v.y = pkbf(fabsf(t0.z - d0.z), fabsf(t0.w - d0.w));
            v.z = pkbf(fabsf(t1.x - d1.x), fabsf(t1.y - d1.y));
            v.w = pkbf(fabsf(t1.z - d1.z), fabsf(t1.w - d1.w));
            *(uint4*)&Ash[(size_t)(((kstep * 2 + pt) * 2 + lh) * 32 + m) * 8] = v;
        }
    }

    // ---- C-init: acc = P[n,h] + Q[m,h]; pair p = pt*32 + l32 -> n = pt*4 + (l32>>3), m = lane&7
    const float* Pb = P + (size_t)(b * 128 + n0) * H_DIM;
    const float* Qb = Q + (size_t)(b * 128 + m0) * H_DIM;
    f32x16 acc[2][2];
    {
        int mq = lane & 7;
        f32x4 qv[2][4];
#pragma unroll
        for (int ht = 0; ht < 2; ++ht)
#pragma unroll
            for (int rq = 0; rq < 4; ++rq)
                qv[ht][rq] = *(const f32x4*)&Qb[(size_t)mq * H_DIM + wave * 64 + ht * 32 + rq * 8 + lh * 4];
#pragma unroll
        for (int pt = 0; pt < 2; ++pt) {
            int n = pt * 4 + (l32 >> 3);
#pragma unroll
            for (int ht = 0; ht < 2; ++ht)
#pragma unroll
                for (int rq = 0; rq < 4; ++rq) {
                    f32x4 pv = *(const f32x4*)&Pb[(size_t)n * H_DIM + wave * 64 + ht * 32 + rq * 8 + lh * 4];
                    f32x4 s = pv + qv[ht][rq];
#pragma unroll
                    for (int j = 0; j < 4; ++j) acc[pt][ht][rq * 4 + j] = s[j];
                }
        }
    }
    __syncthreads();

    // ---- K-loop: 16 ksteps, 4 MFMA each; B 4-slot rotation, prefetch distance 2
#pragma unroll 4
    for (int ks = 0; ks < 16; ++ks) {
        if (ks < 14) {
#pragma unroll
            for (int ht = 0; ht < 2; ++ht)
                bw[(ks + 2) & 3][ht] = __builtin_bit_cast(bf16x8,
                    Wg2[((ks + 2) * 16 + wave * 2 + ht) * 64 + lane]);
        }
#pragma unroll
        for (int pt = 0; pt < 2; ++pt) {
            bf16x8 af = *(const bf16x8*)&Ash[(size_t)((ks * 2 + pt) * 64 + lane) * 8];
#pragma unroll
            for (int ht = 0; ht < 2; ++ht)
                acc[pt][ht] = __builtin_amdgcn_mfma_f32_32x32x16_bf16(bw[ks & 3][ht], af, acc[pt][ht], 0, 0, 0);
        }
    }

    // ---- phase B: LN partials: in-register sum over 32 h-values, 1 shuffle (xor 32)
#pragma unroll
    for (int pt = 0; pt < 2; ++pt) {
        float s1 = 0.f, s2 = 0.f;
#pragma unroll
        for (int ht = 0; ht < 2; ++ht)
#pragma unroll
            for (int r = 0; r < 16; ++r) {
                float v = acc[pt][ht][r];
                s1 += v; s2 += v * v;
            }
        s1 += __shfl_xor(s1, 32); s2 += __shfl_xor(s2, 32);
        if (lane < 32) {
            LNr1[(pt * 32 + l32) * 9 + wave] = s1;
            LNr2[(pt * 32 + l32) * 9 + wave] = s2;
        }
    }
    __syncthreads();
    {   // all-wave reduce: wave w handles pairs w*8..w*8+7
        int pair = wave * 8 + (lane >> 3);
        int idx  = lane & 7;
        float s1 = LNr1[pair * 9 + idx];
        float s2 = LNr2[pair * 9 + idx];
        s1 += __shfl_xor(s1, 1); s2 += __shfl_xor(s2, 1);
        s1 += __shfl_xor(s1, 2); s2 += __shfl_xor(s2, 2);
        s1 += __shfl_xor(s1, 4); s2 += __shfl_xor(s2, 4);
        if ((lane & 7) == 0) {
            float mu = s1 * (1.0f / 512.0f);
            float var = s2 * (1.0f / 512.0f) - mu * mu;
            MuS[pair] = mu;
            RsS[pair] = rsqrtf(var + 1e-5f);
        }
    }
    __syncthreads();

    // ---- phase C: normalize + SiLU + W2 partial dot
    float mus[2], rss[2];
#pragma unroll
    for (int pt = 0; pt < 2; ++pt) { mus[pt] = MuS[pt * 32 + l32]; rss[pt] = RsS[pt * 32 + l32]; }
    float ca[2] = {0.f, 0.f};
#pragma unroll
    for (int ht = 0; ht < 2; ++ht) {
#pragma unroll
        for (int rq = 0; rq < 4; ++rq) {
            int h = wave * 64 + ht * 32 + rq * 8 + lh * 4;
            f32x4 g  = *(const f32x4*)&gamma[h];
            f32x4 bb = *(const f32x4*)&beta[h];
            f32x4 w  = *(const f32x4*)&W2[h];
#pragma unroll
            for (int pt = 0; pt < 2; ++pt) {
#pragma unroll
                for (int j = 0; j < 4; ++j) {
                    float x = (acc[pt][ht][rq * 4 + j] - mus[pt]) * rss[pt] * g[j] + bb[j];
                    float sg = __builtin_amdgcn_rcpf(1.0f + __expf(-x));
                    ca[pt] += x * sg * w[j];
                }
            }
        }
    }
#pragma unroll
    for (int pt = 0; pt < 2; ++pt) {
        float c = ca[pt];
        c += __shfl_xor(c, 32);
        if (lane < 32) Red2[(pt * 32 + l32) * 9 + wave] = c;
    }
    __syncthreads();
    {   // all-wave out reduce
        int pair = wave * 8 + (lane >> 3);
        float c = Red2[pair * 9 + (lane & 7)];
        c += __shfl_xor(c, 1);
        c += __shfl_xor(c, 2);
        c += __shfl_xor(c, 4);
        if ((lane & 7) == 0) {
            float o = c + b2[0];
            int n = n0 + (pair >> 3);
            int m = m0 + (pair & 7);
            out[(size_t)(b * 128 + n) * 128 + m] = o;
        }
    }
}

extern "C" void kernel_launch(void* const* d_in, const int* in_sizes, int n_in,
                              void* d_out, int out_size, void* d_ws, size_t ws_size,
                              hipStream_t stream) {
    const float* track = (const float*)d_in[0];
    const float* det   = (const float*)d_in[1];
    const float* W1    = (const float*)d_in[2];
    const float* b1    = (const float*)d_in[3];
    const float* gamma = (const float*)d_in[4];
    const float* beta  = (const float*)d_in[5];
    const float* W2    = (const float*)d_in[6];
    const float* b2    = (const float*)d_in[7];
    float* out = (float*)d_out;

    char* ws = (char*)d_ws;
    float*  P     = (float*)(ws);                      // 2 MB  (1024 x 512 f32)
    float*  Q     = (float*)(ws + (2u << 20));         // 2 MB
    __bf16* W1cc  = (__bf16*)(ws + (4u << 20));        // 768 KB (mats 0/1 old layout, mat2 32x32-frag layout)

    w1conv_kernel<<<192, 256, 0, stream>>>(W1, W1cc);
    pq_mfma_kernel<<<128, 512, 0, stream>>>(track, det, W1cc, b1, P, Q);
    main_kernel<<<2048, 512, 0, stream>>>(track, det, W1cc, P, Q, gamma, beta, W2, b2, out);
}

// Round 12
// 152.472 us; speedup vs baseline: 1.0716x; 1.0716x over previous
//
#include <hip/hip_runtime.h>
#include <hip/hip_bf16.h>
#include <cstdint>

typedef __bf16 bf16x8 __attribute__((ext_vector_type(8)));
typedef __bf16 bf16x2 __attribute__((ext_vector_type(2)));
typedef float f32x4 __attribute__((ext_vector_type(4)));

#define E_DIM 256
#define H_DIM 512
#define TSTR 260   // padded f32 row stride (1040 B: 16B-aligned rows, odd 16B-groups)

// packed f32x2 -> bf16x2 (RNE): lowers to v_cvt_pk_bf16_f32 on gfx950
static __device__ __forceinline__ unsigned pkbf(float a, float b) {
    bf16x2 h;
    h[0] = (__bf16)a;
    h[1] = (__bf16)b;
    return __builtin_bit_cast(unsigned, h);
}

// ---------------- kernel 1: W1 (all 3 blocks) -> bf16 chunk-major [mat][c][h][kk] ----------------
__global__ __launch_bounds__(256)
void w1conv_kernel(const float* __restrict__ W1, __bf16* __restrict__ W1cc) {
    int u = blockIdx.x * 256 + threadIdx.x;   // 0..49151
    int j   = u & 3;
    int h   = (u >> 2) & 511;
    int c   = (u >> 11) & 7;
    int mat = u >> 14;                        // 0..2
    const float* src = W1 + (size_t)(mat * 256 + c * 32 + j * 8) * H_DIM + h;
    uint4 v;
    v.x = pkbf(src[0], src[(size_t)1 * H_DIM]);
    v.y = pkbf(src[(size_t)2 * H_DIM], src[(size_t)3 * H_DIM]);
    v.z = pkbf(src[(size_t)4 * H_DIM], src[(size_t)5 * H_DIM]);
    v.w = pkbf(src[(size_t)6 * H_DIM], src[(size_t)7 * H_DIM]);
    *(uint4*)(W1cc + ((size_t)(mat * 8 + c) * 512 + h) * 32 + j * 8) = v;
}

// ---------------- kernel 2: P = norm(t)@W1a + b1 ; Q = norm(d)@W1b via bf16 MFMA ----------------
// 128 blocks x 512 thr. Block = 32 rows x 256 h. Wave covers 32 rows x 32 h.
__global__ __launch_bounds__(512, 4)
void pq_mfma_kernel(const float* __restrict__ track, const float* __restrict__ det,
                    const __bf16* __restrict__ W1cc, const float* __restrict__ b1,
                    float* __restrict__ P, float* __restrict__ Q) {
    __shared__ __align__(16) __bf16 Ash[32 * 256];   // 16 KB
    __shared__ float sclS[32];

    int tid  = threadIdx.x;
    int lane = tid & 63;
    int wave = tid >> 6;
    int lq   = lane >> 4;
    int lc   = lane & 15;

    int blk  = blockIdx.x;
    int mat  = blk >> 6;               // 0 = P(track), 1 = Q(det)
    int rowg = (blk >> 1) & 31;
    int half = blk & 1;
    int r0   = rowg * 32;
    int h0   = half * 256;
    const float* src = mat ? det : track;

#pragma unroll
    for (int i = 0; i < 4; ++i) {
        int row = wave * 4 + i;
        float4 x = ((const float4*)(src + (size_t)(r0 + row) * E_DIM))[lane];
        float ss = x.x*x.x + x.y*x.y + x.z*x.z + x.w*x.w;
#pragma unroll
        for (int off = 32; off > 0; off >>= 1) ss += __shfl_xor(ss, off);
        if (lane == 0) sclS[row] = 1.0f / fmaxf(sqrtf(ss), 1e-12f);
    }
    __syncthreads();

#pragma unroll
    for (int r = 0; r < 2; ++r) {
        int row = r * 16 + lc;
        float st = sclS[row];
        const float* gp = src + (size_t)(r0 + row) * E_DIM + wave * 32 + lq * 8;
        float4 t0 = *(const float4*)gp;
        float4 t1 = *(const float4*)(gp + 4);
        uint4 v;
        v.x = pkbf(t0.x * st, t0.y * st);
        v.y = pkbf(t0.z * st, t0.w * st);
        v.z = pkbf(t1.x * st, t1.y * st);
        v.w = pkbf(t1.z * st, t1.w * st);
        *(uint4*)&Ash[(size_t)(r * 512 + wave * 64 + lane) * 8] = v;
    }
    __syncthreads();

    const uint4* Wg = (const uint4*)W1cc + (mat ? 16384 : 0);
    int hb = h0 + wave * 32 + lc;
    bf16x8 bwA[2], bwB[2];
#pragma unroll
    for (int ht = 0; ht < 2; ++ht)
        bwA[ht] = __builtin_bit_cast(bf16x8, Wg[(hb + ht * 16) * 4 + lq]);

    f32x4 acc[2][2];
#pragma unroll
    for (int pt = 0; pt < 2; ++pt)
#pragma unroll
        for (int ht = 0; ht < 2; ++ht)
            acc[pt][ht] = (f32x4){0.f, 0.f, 0.f, 0.f};

#pragma unroll 2
    for (int c = 0; c < 8; ++c) {
        bf16x8* cur = (c & 1) ? bwB : bwA;
        bf16x8* nxt = (c & 1) ? bwA : bwB;
        int c1 = (c + 1) & 7;
#pragma unroll
        for (int ht = 0; ht < 2; ++ht)
            nxt[ht] = __builtin_bit_cast(bf16x8, Wg[c1 * 2048 + (hb + ht * 16) * 4 + lq]);
#pragma unroll
        for (int pt = 0; pt < 2; ++pt) {
            bf16x8 af = *(const bf16x8*)&Ash[(size_t)((pt * 8 + c) * 64 + lane) * 8];
#pragma unroll
            for (int ht = 0; ht < 2; ++ht)
                acc[pt][ht] = __builtin_amdgcn_mfma_f32_16x16x32_bf16(cur[ht], af, acc[pt][ht], 0, 0, 0);
        }
    }

    float* dst = mat ? Q : P;
#pragma unroll
    for (int ht = 0; ht < 2; ++ht) {
        int h = h0 + wave * 32 + ht * 16 + lq * 4;
        f32x4 bvv = (f32x4){0.f, 0.f, 0.f, 0.f};
        if (!mat) bvv = *(const f32x4*)&b1[h];
#pragma unroll
        for (int pt = 0; pt < 2; ++pt) {
            f32x4 o = acc[pt][ht] + bvv;
            *(f32x4*)&dst[(size_t)(r0 + pt * 16 + lc) * H_DIM + h] = o;
        }
    }
}

// ---------------- kernel 3: fused pairwise GEMM + LN + SiLU + W2 dot ----------------
// grid 2048 x 512 thr (8 waves). Block: 64 pairs x 512 H; K=256, 8 chunks. (R10 structure)
// C layout [h x pair]; A = W1c frags (register dbuf); B = |t-d| frags from LDS.
// R12 deltas vs R10: rows pre-scaled at stage time (A-stage loses 64 muls + scl LDS reads);
// LN mid-reduce and out-reduce spread across all 8 waves (no 1-wave serial section).
__global__ __launch_bounds__(512, 4)
void main_kernel(const float* __restrict__ track, const float* __restrict__ det,
                 const __bf16* __restrict__ W1cc,
                 const float* __restrict__ P, const float* __restrict__ Q,
                 const float* __restrict__ gamma, const float* __restrict__ beta,
                 const float* __restrict__ W2, const float* __restrict__ b2,
                 float* __restrict__ out) {
    __shared__ __align__(16) char SMEM[49408];
    __bf16* Ash  = (__bf16*)SMEM;                     // [0,32768) phase 1+2
    float*  tsl  = (float*)(SMEM + 32768);            // 8*TSTR f32 (pre-scaled rows), phase 1
    float*  dsl  = (float*)(SMEM + 41088);            // phase 1
    float*  LNr1 = (float*)(SMEM + 32768);            // [64][9] phase 2 (tsl dead)
    float*  LNr2 = (float*)(SMEM + 35072);            // [64][9]
    float*  Red2 = (float*)(SMEM + 37376);            // [64][9]
    float*  MuS  = (float*)(SMEM + 39680);            // [64]
    float*  RsS  = (float*)(SMEM + 39936);            // [64]

    int tid  = threadIdx.x;
    int lane = tid & 63;
    int wave = tid >> 6;
    int lq   = lane >> 4;
    int lc   = lane & 15;

    int blk = blockIdx.x;
    int b   = blk >> 8;
    int n0  = ((blk >> 4) & 15) * 8;
    int m0  = (blk & 15) * 8;

    // ---- stage loads: wave w holds row w of t-slice and d-slice
    float4 tstage = ((const float4*)(track + (size_t)(b * 128 + n0 + wave) * E_DIM))[lane];
    float4 dstage = ((const float4*)(det   + (size_t)(b * 128 + m0 + wave) * E_DIM))[lane];

    // ---- W1c frags, chunk-0 prefetch (mat 2 base = 32768 uint4)
    const uint4* Wg = (const uint4*)W1cc + 32768;
    int hb = wave * 64 + lc;
    bf16x8 bwA[4], bwB[4];
#pragma unroll
    for (int ht = 0; ht < 4; ++ht)
        bwA[ht] = __builtin_bit_cast(bf16x8, Wg[(hb + ht * 16) * 4 + lq]);

    // ---- row norms (butterfly -> all lanes) + pre-scale in registers, then LDS write
    {
        float a = tstage.x*tstage.x + tstage.y*tstage.y + tstage.z*tstage.z + tstage.w*tstage.w;
        float d = dstage.x*dstage.x + dstage.y*dstage.y + dstage.z*dstage.z + dstage.w*dstage.w;
#pragma unroll
        for (int off = 32; off > 0; off >>= 1) { a += __shfl_xor(a, off); d += __shfl_xor(d, off); }
        float st = 1.0f / fmaxf(sqrtf(a), 1e-12f);
        float sd = 1.0f / fmaxf(sqrtf(d), 1e-12f);
        tstage.x *= st; tstage.y *= st; tstage.z *= st; tstage.w *= st;
        dstage.x *= sd; dstage.y *= sd; dstage.z *= sd; dstage.w *= sd;
    }
    *(float4*)&tsl[wave * TSTR + lane * 4] = tstage;
    *(float4*)&dsl[wave * TSTR + lane * 4] = dstage;
    __syncthreads();

    // ---- A-stage: iter r covers pair p = r*16+lc, k = wave*32+lq*8 .. +7 (rows pre-scaled)
    {
        int k0 = wave * 32 + lq * 8;
        int ml = lane & 7;
        const float* dr = dsl + ml * TSTR + k0;
        float4 d0 = *(const float4*)dr;
        float4 d1 = *(const float4*)(dr + 4);
#pragma unroll
        for (int r = 0; r < 4; ++r) {
            int nl = r * 2 + (lc >> 3);
            const float* tr = tsl + nl * TSTR + k0;
            float4 t0 = *(const float4*)tr;
            float4 t1 = *(const float4*)(tr + 4);
            uint4 v;
            v.x = pkbf(fabsf(t0.x - d0.x), fabsf(t0.y - d0.y));
            v.y = pkbf(fabsf(t0.z - d0.z), fabsf(t0.w - d0.w));
            v.z = pkbf(fabsf(t1.x - d1.x), fabsf(t1.y - d1.y));
            v.w = pkbf(fabsf(t1.z - d1.z), fabsf(t1.w - d1.w));
            *(uint4*)&Ash[(size_t)(r * 512 + wave * 64 + lane) * 8] = v;
        }
    }

    // ---- C-init: acc = P[n,h] + Q[m,h] (L2-resident, vector f32x4) — fused into MFMA C
    const float* Pb = P + (size_t)(b * 128 + n0) * H_DIM;
    const float* Qb = Q + (size_t)(b * 128 + m0) * H_DIM;
    f32x4 acc[4][4];
    {
        f32x4 qv[4];
#pragma unroll
        for (int ht = 0; ht < 4; ++ht)
            qv[ht] = *(const f32x4*)&Qb[(size_t)(lc & 7) * H_DIM + wave * 64 + ht * 16 + lq * 4];
#pragma unroll
        for (int pt = 0; pt < 4; ++pt) {
            int n = pt * 2 + (lc >> 3);
#pragma unroll
            for (int ht = 0; ht < 4; ++ht) {
                f32x4 pv = *(const f32x4*)&Pb[(size_t)n * H_DIM + wave * 64 + ht * 16 + lq * 4];
                acc[pt][ht] = pv + qv[ht];
            }
        }
    }
    __syncthreads();

    // ---- K-loop: zero barriers; unroll-2 keeps ping-pong dbuf, bounds register liveness
#pragma unroll 2
    for (int c = 0; c < 8; ++c) {
        bf16x8* cur = (c & 1) ? bwB : bwA;
        bf16x8* nxt = (c & 1) ? bwA : bwB;
        int c1 = (c + 1) & 7;
#pragma unroll
        for (int ht = 0; ht < 4; ++ht)
            nxt[ht] = __builtin_bit_cast(bf16x8, Wg[c1 * 2048 + (hb + ht * 16) * 4 + lq]);
#pragma unroll
        for (int pt = 0; pt < 4; ++pt) {
            bf16x8 af = *(const bf16x8*)&Ash[(size_t)((pt * 8 + c) * 64 + lane) * 8];
#pragma unroll
            for (int ht = 0; ht < 4; ++ht)
                acc[pt][ht] = __builtin_amdgcn_mfma_f32_16x16x32_bf16(cur[ht], af, acc[pt][ht], 0, 0, 0);
        }
    }

    // ---- phase B: LN partials: in-register sum over 16 h-values, 2 shuffles across lq
#pragma unroll
    for (int pt = 0; pt < 4; ++pt) {
        float s1 = 0.f, s2 = 0.f;
#pragma unroll
        for (int ht = 0; ht < 4; ++ht)
#pragma unroll
            for (int rg = 0; rg < 4; ++rg) {
                float v = acc[pt][ht][rg];
                s1 += v; s2 += v * v;
            }
        s1 += __shfl_xor(s1, 16); s2 += __shfl_xor(s2, 16);
        s1 += __shfl_xor(s1, 32); s2 += __shfl_xor(s2, 32);
        if (lq == 0) {
            LNr1[(pt * 16 + lc) * 9 + wave] = s1;
            LNr2[(pt * 16 + lc) * 9 + wave] = s2;
        }
    }
    __syncthreads();
    {   // all-wave mid-reduce: wave w handles pairs w*8..w*8+7
        int pair = wave * 8 + (lane >> 3);
        int idx  = lane & 7;
        float s1 = LNr1[pair * 9 + idx];
        float s2 = LNr2[pair * 9 + idx];
        s1 += __shfl_xor(s1, 1); s2 += __shfl_xor(s2, 1);
        s1 += __shfl_xor(s1, 2); s2 += __shfl_xor(s2, 2);
        s1 += __shfl_xor(s1, 4); s2 += __shfl_xor(s2, 4);
        if ((lane & 7) == 0) {
            float mu = s1 * (1.0f / 512.0f);
            float var = s2 * (1.0f / 512.0f) - mu * mu;
            MuS[pair] = mu;
            RsS[pair] = rsqrtf(var + 1e-5f);
        }
    }
    __syncthreads();

    // ---- phase C: normalize + SiLU + W2 partial dot (per-ht transient param loads)
    float mus[4], rss[4];
#pragma unroll
    for (int pt = 0; pt < 4; ++pt) { mus[pt] = MuS[pt * 16 + lc]; rss[pt] = RsS[pt * 16 + lc]; }
    float ca[4] = {0.f, 0.f, 0.f, 0.f};
#pragma unroll
    for (int ht = 0; ht < 4; ++ht) {
        int h = wave * 64 + ht * 16 + lq * 4;
        f32x4 g  = *(const f32x4*)&gamma[h];
        f32x4 bb = *(const f32x4*)&beta[h];
        f32x4 w  = *(const f32x4*)&W2[h];
#pragma unroll
        for (int pt = 0; pt < 4; ++pt) {
#pragma unroll
            for (int rg = 0; rg < 4; ++rg) {
                float x = (acc[pt][ht][rg] - mus[pt]) * rss[pt] * g[rg] + bb[rg];
                float sg = __builtin_amdgcn_rcpf(1.0f + __expf(-x));
                ca[pt] += x * sg * w[rg];
            }
        }
    }
#pragma unroll
    for (int pt = 0; pt < 4; ++pt) {
        float c = ca[pt];
        c += __shfl_xor(c, 16);
        c += __shfl_xor(c, 32);
        if (lq == 0) Red2[(pt * 16 + lc) * 9 + wave] = c;
    }
    __syncthreads();
    {   // all-wave out reduce: wave w handles pairs w*8..w*8+7
        int pair = wave * 8 + (lane >> 3);
        float c = Red2[pair * 9 + (lane & 7)];
        c += __shfl_xor(c, 1);
        c += __shfl_xor(c, 2);
        c += __shfl_xor(c, 4);
        if ((lane & 7) == 0) {
            float o = c + b2[0];
            int n = n0 + (pair >> 3);
            int m = m0 + (pair & 7);
            out[(size_t)(b * 128 + n) * 128 + m] = o;
        }
    }
}

extern "C" void kernel_launch(void* const* d_in, const int* in_sizes, int n_in,
                              void* d_out, int out_size, void* d_ws, size_t ws_size,
                              hipStream_t stream) {
    const float* track = (const float*)d_in[0];
    const float* det   = (const float*)d_in[1];
    const float* W1    = (const float*)d_in[2];
    const float* b1    = (const float*)d_in[3];
    const float* gamma = (const float*)d_in[4];
    const float* beta  = (const float*)d_in[5];
    const float* W2    = (const float*)d_in[6];
    const float* b2    = (const float*)d_in[7];
    float* out = (float*)d_out;

    char* ws = (char*)d_ws;
    float*  P     = (float*)(ws);                      // 2 MB  (1024 x 512 f32)
    float*  Q     = (float*)(ws + (2u << 20));         // 2 MB
    __bf16* W1cc  = (__bf16*)(ws + (4u << 20));        // 768 KB (bf16 chunk-major, 3 mats)

    w1conv_kernel<<<192, 256, 0, stream>>>(W1, W1cc);
    pq_mfma_kernel<<<128, 512, 0, stream>>>(track, det, W1cc, b1, P, Q);
    main_kernel<<<2048, 512, 0, stream>>>(track, det, W1cc, P, Q, gamma, beta, W2, b2, out);
}